// Round 11
// baseline (92.613 us; speedup 1.0000x reference)
//
#include <hip/hip_runtime.h>

typedef short bf16x8 __attribute__((ext_vector_type(8)));   // 8 bf16 = 4 VGPRs
typedef float f32x16 __attribute__((ext_vector_type(16)));  // MFMA 32x32 acc
typedef float f32x4  __attribute__((ext_vector_type(4)));

constexpr int B  = 16;
constexpr int H  = 128;
constexpr int CL = 2048;
constexpr int QL = 256;
constexpr int SPLITK5 = 8;
constexpr int K5SEG = CL / SPLITK5;   // 256
constexpr float SHIFT = 8.0f;         // exp shift (overflow-safe, |s| ~ O(6))

__device__ __forceinline__ unsigned short f2bf(float x) {
  unsigned u = __float_as_uint(x);
  u += 0x7fffu + ((u >> 16) & 1u);   // round-to-nearest-even
  return (unsigned short)(u >> 16);
}
__device__ __forceinline__ float bf2f(unsigned short u) {
  return __uint_as_float((unsigned)u << 16);
}

// ---------------- KT: fp32 -> bf16 linear + transposed copies + bias partials ----
// ctx path additionally writes output group 0 (exact fp32 copy, NT stores).
template<int L, bool SCALE, bool WOUT>
__device__ __forceinline__ void ktrans_body(
    const float* __restrict__ src, const float* __restrict__ wbias,
    const float* __restrict__ wscale,
    unsigned short* __restrict__ dlin, unsigned short* __restrict__ dT,
    float* __restrict__ pbias, float* __restrict__ outg0,
    int bxl, int h1, int b, int tid,
    unsigned short (*T)[72], float (*P)[64]) {
  const int c0 = bxl * 64;
  const int hh = tid >> 4;
  const int cc4 = (tid & 15) * 4;
  float4 part = make_float4(0.f, 0.f, 0.f, 0.f);
  #pragma unroll
  for (int it = 0; it < 4; ++it) {
    const int hrow = it * 16 + hh;
    const int h = h1 * 64 + hrow;
    float4 v = *(const float4*)&src[((size_t)b * H + h) * L + c0 + cc4];
    const float wb = wbias[h];
    part.x = fmaf(v.x, wb, part.x); part.y = fmaf(v.y, wb, part.y);
    part.z = fmaf(v.z, wb, part.z); part.w = fmaf(v.w, wb, part.w);
    if (WOUT) {
      f32x4 t;
      t[0] = v.x; t[1] = v.y; t[2] = v.z; t[3] = v.w;
      __builtin_nontemporal_store(
          t, (f32x4*)&outg0[((size_t)b * 4 * H + h) * (size_t)CL + c0 + cc4]);
    }
    ushort4 o;
    o.x = f2bf(v.x); o.y = f2bf(v.y); o.z = f2bf(v.z); o.w = f2bf(v.w);
    *(ushort4*)&dlin[((size_t)b * H + h) * L + c0 + cc4] = o;
    ushort4 ot;
    if (SCALE) {
      const float ws = wscale[h];
      ot.x = f2bf(v.x * ws); ot.y = f2bf(v.y * ws);
      ot.z = f2bf(v.z * ws); ot.w = f2bf(v.w * ws);
    } else {
      ot = o;
    }
    *(ushort4*)&T[hrow][cc4] = ot;
  }
  *(float4*)&P[hh][cc4] = part;
  __syncthreads();
  if (tid < 64) {
    float sum = 0.f;
    #pragma unroll
    for (int i = 0; i < 16; ++i) sum += P[i][tid];
    pbias[(size_t)h1 * B * L + (size_t)b * L + c0 + tid] = sum;
  }
  #pragma unroll
  for (int it = 0; it < 4; ++it) {
    int lin = it * 256 + tid;
    int c = lin >> 4, hc = (lin & 15) * 4;
    ushort4 o;
    o.x = T[hc + 0][c]; o.y = T[hc + 1][c];
    o.z = T[hc + 2][c]; o.w = T[hc + 3][c];
    *(ushort4*)&dT[((size_t)b * L + c0 + c) * H + h1 * 64 + hc] = o;
  }
}

__global__ __launch_bounds__(256) void ktrans_all(
    const float* __restrict__ ctx, const float* __restrict__ qry,
    const float* __restrict__ w,
    unsigned short* __restrict__ ctx_bf, unsigned short* __restrict__ ctxwT,
    unsigned short* __restrict__ qry_bf, unsigned short* __restrict__ qryT,
    float* __restrict__ pct, float* __restrict__ pqt,
    float* __restrict__ out) {
  __shared__ unsigned short T[64][72];
  __shared__ float P[16][64];
  const int h1 = blockIdx.y, b = blockIdx.z, tid = threadIdx.x;
  const int bx = blockIdx.x;
  if (bx < CL / 64) {
    ktrans_body<CL, true, true>(ctx, w + H, w + 2 * H, ctx_bf, ctxwT, pct, out,
                                bx, h1, b, tid, T, P);
  } else {
    ktrans_body<QL, false, false>(qry, w, w, qry_bf, qryT, pqt, nullptr,
                                  bx - CL / 64, h1, b, tid, T, P);
  }
}

// ---------------- K2: MFMA score ONCE + shifted exp; emit s1u[c][q] (NT),
// s2u[q][c], rsum[b][c], Lpart. Single-barrier: dual LDS tiles.
__global__ __launch_bounds__(512) void k2_score2(
    const unsigned short* __restrict__ ctxwT, const unsigned short* __restrict__ qryT,
    const float* __restrict__ pct, const float* __restrict__ pqt,
    const int* __restrict__ cmask, const int* __restrict__ qmask,
    unsigned short* __restrict__ s1u, unsigned short* __restrict__ s2u,
    float* __restrict__ rsum_g, float* __restrict__ Lpart) {
  __shared__ unsigned short t1[32 * 264];   // [32 c][264 q] qmasked e
  __shared__ unsigned short t2[256 * 40];   // [256 q][40 c] cmasked e
  __shared__ float stats[32][8];
  const int wg = blockIdx.x;
  const int b = wg & (B - 1);          // innermost -> XCD locality for qryT
  const int cblk = wg >> 4;
  const int c0 = cblk * 32;
  const int tid = threadIdx.x;
  const int w = tid >> 6;
  const int l = tid & 63;
  const int lr = l & 31, hi = l >> 5;
  const int q0 = w * 32;
  const int c = c0 + lr;

  // score MFMA: A = qryT rows (M=q), B = ctxwT rows (N=c), K=H=128
  const unsigned short* ap = qryT + ((size_t)b * QL + q0 + lr) * H + hi * 8;
  const unsigned short* bp = ctxwT + ((size_t)b * CL + c) * H + hi * 8;
  f32x16 acc = {};
  #pragma unroll
  for (int k = 0; k < H; k += 16) {
    bf16x8 af = *(const bf16x8*)(ap + k);
    bf16x8 bf_ = *(const bf16x8*)(bp + k);
    acc = __builtin_amdgcn_mfma_f32_32x32x16_bf16(af, bf_, acc, 0, 0, 0);
  }

  const float ct = pct[b * CL + c] + pct[B * CL + b * CL + c];
  const bool cm = cmask[b * CL + c] > 0;

  float e[16];       // raw exp(s - SHIFT)
  unsigned qmb = 0;
  #pragma unroll
  for (int g = 0; g < 4; ++g) {
    const int qbase = q0 + 4 * hi + 8 * g;
    float4 qa = *(const float4*)&pqt[b * QL + qbase];
    float4 qb = *(const float4*)&pqt[B * QL + b * QL + qbase];
    int4 m4 = *(const int4*)&qmask[b * QL + qbase];
    e[4 * g + 0] = __expf(acc[4 * g + 0] + ct + qa.x + qb.x - SHIFT);
    e[4 * g + 1] = __expf(acc[4 * g + 1] + ct + qa.y + qb.y - SHIFT);
    e[4 * g + 2] = __expf(acc[4 * g + 2] + ct + qa.z + qb.z - SHIFT);
    e[4 * g + 3] = __expf(acc[4 * g + 3] + ct + qa.w + qb.w - SHIFT);
    qmb |= (m4.x > 0 ? 1u : 0u) << (4 * g + 0);
    qmb |= (m4.y > 0 ? 1u : 0u) << (4 * g + 1);
    qmb |= (m4.z > 0 ? 1u : 0u) << (4 * g + 2);
    qmb |= (m4.w > 0 ? 1u : 0u) << (4 * g + 3);
  }

  // s1 tile (qmasked) + row-sum; s2 tile (cmasked) -- both before ONE barrier
  float rs = 0.f;
  #pragma unroll
  for (int g = 0; g < 4; ++g) {
    ushort4 o;
    #pragma unroll
    for (int j = 0; j < 4; ++j) {
      const float ev = ((qmb >> (4 * g + j)) & 1u) ? e[4 * g + j] : 0.f;
      rs += ev;
      (&o.x)[j] = f2bf(ev);
    }
    *(ushort4*)&t1[lr * 264 + q0 + 4 * hi + 8 * g] = o;
  }
  rs += __shfl_xor(rs, 32);
  if (hi == 0) stats[lr][w] = rs;
  #pragma unroll
  for (int g = 0; g < 4; ++g) {
    const int qbase = q0 + 4 * hi + 8 * g;
    #pragma unroll
    for (int j = 0; j < 4; ++j)
      t2[(qbase + j) * 40 + lr] = f2bf(cm ? e[4 * g + j] : 0.f);
  }
  __syncthreads();

  // epilogue: rsum, s1 copy-out (NT), s2 copy-out + Lpart -- all unordered
  if (tid < 32) {
    float s = 0.f;
    #pragma unroll
    for (int ww = 0; ww < 8; ++ww) s += stats[tid][ww];
    rsum_g[b * CL + c0 + tid] = s;
  }
  {
    const int row = tid >> 4, qo = (tid & 15) * 16;
    bf16x8 v0 = *(const bf16x8*)&t1[row * 264 + qo];
    bf16x8 v1 = *(const bf16x8*)&t1[row * 264 + qo + 8];
    unsigned short* op = s1u + ((size_t)b * CL + c0 + row) * QL + qo;
    __builtin_nontemporal_store(v0, (bf16x8*)op);
    __builtin_nontemporal_store(v1, (bf16x8*)(op + 8));
  }
  {
    const int q = tid >> 1, co = (tid & 1) * 16;
    bf16x8 v0 = *(const bf16x8*)&t2[q * 40 + co];
    bf16x8 v1 = *(const bf16x8*)&t2[q * 40 + co + 8];
    float cs = 0.f;
    #pragma unroll
    for (int i2 = 0; i2 < 8; ++i2) {
      cs += bf2f((unsigned short)v0[i2]);
      cs += bf2f((unsigned short)v1[i2]);
    }
    cs += __shfl_xor(cs, 1);
    unsigned short* op = s2u + ((size_t)b * QL + q) * CL + c0 + co;
    *(bf16x8*)op = v0;
    *(bf16x8*)(op + 8) = v1;
    if ((tid & 1) == 0) Lpart[((size_t)b * 64 + cblk) * QL + q] = cs;
  }
}

// ---------------- K5: MFMA tpart[seg][b][q][h] = sum_{c in seg} s2u[q,c]*ctx[h,c] ---
// 1D grid 1024: (b,seg) inner, q0 outer -> ctx_bf sharers co-XCD. 8 blocks/CU.
__global__ __launch_bounds__(256, 8) void k5_tpart(
    const unsigned short* __restrict__ s2u,
    const unsigned short* __restrict__ ctxbf,
    unsigned short* __restrict__ tpart) {
  const int wg = blockIdx.x;
  const int b = wg & (B - 1);
  const int seg = (wg >> 4) & (SPLITK5 - 1);
  const int q0 = (wg >> 7) * 32;
  const int w = threadIdx.x >> 6, l = threadIdx.x & 63;
  const int h0 = w * 32;
  const int lr = l & 31, lg = l >> 5;
  const unsigned short* ap = s2u + ((size_t)b * QL + q0 + lr) * CL + seg * K5SEG + lg * 8;
  const unsigned short* bp = ctxbf + ((size_t)b * H + h0 + lr) * CL + seg * K5SEG + lg * 8;
  f32x16 acc = {};
  #pragma unroll
  for (int k = 0; k < K5SEG; k += 16) {
    bf16x8 af = *(const bf16x8*)(ap + k);
    bf16x8 bfr = *(const bf16x8*)(bp + k);
    acc = __builtin_amdgcn_mfma_f32_32x32x16_bf16(af, bfr, acc, 0, 0, 0);
  }
  unsigned short* tp = tpart + (size_t)(seg * B + b) * QL * H;
  #pragma unroll
  for (int r = 0; r < 16; ++r) {
    int qrow = (r & 3) + 8 * (r >> 2) + 4 * lg;
    tp[(size_t)(q0 + qrow) * H + h0 + lr] = f2bf(acc[r]);
  }
}

// ---------------- K5b: cinv from Lpart + reduce tpart, write tT_bf[b][h][q] ----
// grid (QL/64, H/32, B) = 256 blocks.
__global__ __launch_bounds__(256) void k5b_treduce(
    const unsigned short* __restrict__ tpart, const float* __restrict__ Lpart,
    unsigned short* __restrict__ tTbf) {
  __shared__ unsigned short lds[32 * 66];
  __shared__ float csum[4][64];
  __shared__ float cinv_s[64];
  const int q0 = blockIdx.x * 64, h0 = blockIdx.y * 32, b = blockIdx.z;
  const int tid = threadIdx.x;
  {  // cinv for this block's 64 q's
    const int qq = tid & 63, part = tid >> 6;
    float Ls = 0.f;
    #pragma unroll
    for (int k = 0; k < 16; ++k)
      Ls += Lpart[((size_t)b * 64 + part * 16 + k) * QL + q0 + qq];
    csum[part][qq] = Ls;
  }
  __syncthreads();
  if (tid < 64)
    cinv_s[tid] = 1.0f / (csum[0][tid] + csum[1][tid] + csum[2][tid] + csum[3][tid]);
  __syncthreads();
  for (int lin = tid; lin < 64 * 32; lin += 256) {
    int q = lin >> 5, h = lin & 31;
    float v = 0.f;
    #pragma unroll
    for (int sgt = 0; sgt < SPLITK5; ++sgt)
      v += bf2f(tpart[((size_t)(sgt * B + b) * QL + q0 + q) * H + h0 + h]);
    lds[h * 66 + q] = f2bf(v * cinv_s[q]);
  }
  __syncthreads();
  for (int lin = tid; lin < 32 * 64; lin += 256) {
    int h = lin >> 6, q = lin & 63;
    tTbf[((size_t)b * H + h0 + h) * QL + q0 + q] = lds[h * 66 + q];
  }
}

// ---------------- KB: clean dual-GEMM from s1u + fused output (groups 1..3) ----
// 1D grid 512: b innermost. launch_bounds(512,6): cap VGPR ~85 -> 3 blocks/CU.
__global__ __launch_bounds__(512, 6) void kb_out(
    const unsigned short* __restrict__ s1u,
    const unsigned short* __restrict__ qrybf, const unsigned short* __restrict__ tTbf,
    const unsigned short* __restrict__ ctxbf, const float* __restrict__ rsum_g,
    float* __restrict__ out) {
  __shared__ unsigned short Ps[64 * 264];   // [64 c][264 q] P-tile
  const int wg = blockIdx.x;
  const int b = wg & (B - 1);
  const int c0 = (wg >> 4) * 64;
  const int tid = threadIdx.x;
  const int w = tid >> 6, l = tid & 63;
  const int lr = l & 31, hi = l >> 5;
  const int h0 = (w & 3) * 32;
  const int ch = (w >> 2) * 32;
  const int c = c0 + ch + lr;

  // stage P-tile: 64 rows x 512 B, coalesced
  #pragma unroll
  for (int p = 0; p < 4; ++p) {
    const int idx = p * 512 + tid;
    const int row = idx >> 5, colb = (idx & 31) * 8;
    bf16x8 v = *(const bf16x8*)&s1u[((size_t)b * CL + c0 + row) * QL + colb];
    *(bf16x8*)&Ps[row * 264 + colb] = v;
  }

  const float rinv = 1.0f / rsum_g[b * CL + c];

  // epilogue ctx values (overlap with staging)
  unsigned short cvu[16];
  {
    const unsigned short* cvp = ctxbf + (size_t)b * H * CL + c;
    #pragma unroll
    for (int r = 0; r < 16; ++r) {
      const int h = h0 + (r & 3) + 8 * (r >> 2) + 4 * hi;
      cvu[r] = cvp[(size_t)h * CL];
    }
  }
  __syncthreads();

  // dual GEMM: aT[h,c] = sum_q qry[h,q]*P[c,q]; bT[h,c] = sum_q tT[h,q]*P[c,q]
  const unsigned short* a1p = qrybf + ((size_t)b * H + h0 + lr) * QL + hi * 8;
  const unsigned short* a2p = tTbf + ((size_t)b * H + h0 + lr) * QL + hi * 8;
  f32x16 accA = {}, accB = {};
  #pragma unroll
  for (int kc = 0; kc < 16; ++kc) {
    bf16x8 pb = *(const bf16x8*)&Ps[(ch + lr) * 264 + kc * 16 + hi * 8];
    bf16x8 a1 = *(const bf16x8*)(a1p + kc * 16);
    bf16x8 a2 = *(const bf16x8*)(a2p + kc * 16);
    accA = __builtin_amdgcn_mfma_f32_32x32x16_bf16(a1, pb, accA, 0, 0, 0);
    accB = __builtin_amdgcn_mfma_f32_32x32x16_bf16(a2, pb, accB, 0, 0, 0);
  }
  float* ob = out + (size_t)b * 4 * H * CL;
  #pragma unroll
  for (int r = 0; r < 16; ++r) {
    const int h = h0 + (r & 3) + 8 * (r >> 2) + 4 * hi;
    const float cv = bf2f(cvu[r]);
    const float av = accA[r] * rinv;
    const float bv = accB[r] * rinv;
    __builtin_nontemporal_store(av, &ob[(size_t)(H + h) * CL + c]);
    __builtin_nontemporal_store(cv * av, &ob[(size_t)(2 * H + h) * CL + c]);
    __builtin_nontemporal_store(cv * bv, &ob[(size_t)(3 * H + h) * CL + c]);
  }
}

extern "C" void kernel_launch(void* const* d_in, const int* in_sizes, int n_in,
                              void* d_out, int out_size, void* d_ws, size_t ws_size,
                              hipStream_t stream) {
  const float* context  = (const float*)d_in[0];
  const float* question = (const float*)d_in[1];
  const int*   c_mask   = (const int*)d_in[2];
  const int*   q_mask   = (const int*)d_in[3];
  const float* w        = (const float*)d_in[4];
  float* out = (float*)d_out;

  char* ws = (char*)d_ws;
  size_t off = 0;
  auto alloc = [&](size_t bytes) -> void* {
    void* p = ws + off;
    off += (bytes + 255) & ~(size_t)255;
    return p;
  };
  unsigned short* ctx_bf = (unsigned short*)alloc((size_t)B * H * CL * 2);    // 8.4 MB
  unsigned short* ctxwT  = (unsigned short*)alloc((size_t)B * CL * H * 2);    // 8.4 MB
  unsigned short* qry_bf = (unsigned short*)alloc((size_t)B * H * QL * 2);    // 1.05 MB
  unsigned short* qryT   = (unsigned short*)alloc((size_t)B * QL * H * 2);    // 1.05 MB
  unsigned short* s1u    = (unsigned short*)alloc((size_t)B * CL * QL * 2);   // 16.8 MB
  unsigned short* s2u    = (unsigned short*)alloc((size_t)B * QL * CL * 2);   // 16.8 MB
  unsigned short* tpart  = (unsigned short*)alloc((size_t)SPLITK5 * B * QL * H * 2); // 8.4 MB
  unsigned short* tT_bf  = (unsigned short*)alloc((size_t)B * H * QL * 2);    // 1.05 MB
  float* pct   = (float*)alloc((size_t)2 * B * CL * sizeof(float));
  float* pqt   = (float*)alloc((size_t)2 * B * QL * sizeof(float));
  float* rsum_ = (float*)alloc((size_t)B * CL * sizeof(float));
  float* Lpart = (float*)alloc((size_t)B * 64 * QL * sizeof(float));          // 1 MB

  ktrans_all<<<dim3(CL / 64 + QL / 64, H / 64, B), dim3(256), 0, stream>>>(
      context, question, w, ctx_bf, ctxwT, qry_bf, qryT, pct, pqt, out);

  k2_score2<<<dim3((CL / 32) * B), dim3(512), 0, stream>>>(
      ctxwT, qryT, pct, pqt, c_mask, q_mask, s1u, s2u, rsum_, Lpart);

  k5_tpart<<<dim3((QL / 32) * SPLITK5 * B), dim3(256), 0, stream>>>(
      s2u, ctx_bf, tpart);

  k5b_treduce<<<dim3(QL / 64, H / 32, B), dim3(256), 0, stream>>>(
      tpart, Lpart, tT_bf);

  kb_out<<<dim3((CL / 64) * B), dim3(512), 0, stream>>>(
      s1u, qry_bf, tT_bf, ctx_bf, rsum_, out);
}

// Round 12
// 86.964 us; speedup vs baseline: 1.0650x; 1.0650x over previous
//
#include <hip/hip_runtime.h>

typedef short bf16x8 __attribute__((ext_vector_type(8)));   // 8 bf16 = 4 VGPRs
typedef float f32x16 __attribute__((ext_vector_type(16)));  // MFMA 32x32 acc
typedef float f32x4  __attribute__((ext_vector_type(4)));

constexpr int B  = 16;
constexpr int H  = 128;
constexpr int CL = 2048;
constexpr int QL = 256;
constexpr int SPLITK5 = 8;
constexpr int K5SEG = CL / SPLITK5;   // 256
constexpr float SHIFT = 8.0f;         // exp shift (overflow-safe, |s| ~ O(6))

__device__ __forceinline__ unsigned short f2bf(float x) {
  unsigned u = __float_as_uint(x);
  u += 0x7fffu + ((u >> 16) & 1u);   // round-to-nearest-even
  return (unsigned short)(u >> 16);
}
__device__ __forceinline__ float bf2f(unsigned short u) {
  return __uint_as_float((unsigned)u << 16);
}

// ---------------- KT: fp32 -> bf16 linear + transposed + cmasked copies ----
// ctx path: also writes output group 0 (fp32, NT) and ctxm = cmask? ctx : 0.
template<int L, bool SCALE, bool WOUT, bool CM>
__device__ __forceinline__ void ktrans_body(
    const float* __restrict__ src, const float* __restrict__ wbias,
    const float* __restrict__ wscale, const int* __restrict__ cmask,
    unsigned short* __restrict__ dlin, unsigned short* __restrict__ dT,
    unsigned short* __restrict__ dm,
    float* __restrict__ pbias, float* __restrict__ outg0,
    int bxl, int h1, int b, int tid,
    unsigned short (*T)[72], float (*P)[64]) {
  const int c0 = bxl * 64;
  const int hh = tid >> 4;
  const int cc4 = (tid & 15) * 4;
  int4 cm4;
  if (CM) cm4 = *(const int4*)&cmask[b * L + c0 + cc4];
  float4 part = make_float4(0.f, 0.f, 0.f, 0.f);
  #pragma unroll
  for (int it = 0; it < 4; ++it) {
    const int hrow = it * 16 + hh;
    const int h = h1 * 64 + hrow;
    float4 v = *(const float4*)&src[((size_t)b * H + h) * L + c0 + cc4];
    const float wb = wbias[h];
    part.x = fmaf(v.x, wb, part.x); part.y = fmaf(v.y, wb, part.y);
    part.z = fmaf(v.z, wb, part.z); part.w = fmaf(v.w, wb, part.w);
    if (WOUT) {
      f32x4 t;
      t[0] = v.x; t[1] = v.y; t[2] = v.z; t[3] = v.w;
      __builtin_nontemporal_store(
          t, (f32x4*)&outg0[((size_t)b * 4 * H + h) * (size_t)CL + c0 + cc4]);
    }
    ushort4 o;
    o.x = f2bf(v.x); o.y = f2bf(v.y); o.z = f2bf(v.z); o.w = f2bf(v.w);
    *(ushort4*)&dlin[((size_t)b * H + h) * L + c0 + cc4] = o;
    if (CM) {
      ushort4 om;
      om.x = cm4.x > 0 ? o.x : (unsigned short)0;
      om.y = cm4.y > 0 ? o.y : (unsigned short)0;
      om.z = cm4.z > 0 ? o.z : (unsigned short)0;
      om.w = cm4.w > 0 ? o.w : (unsigned short)0;
      *(ushort4*)&dm[((size_t)b * H + h) * L + c0 + cc4] = om;
    }
    ushort4 ot;
    if (SCALE) {
      const float ws = wscale[h];
      ot.x = f2bf(v.x * ws); ot.y = f2bf(v.y * ws);
      ot.z = f2bf(v.z * ws); ot.w = f2bf(v.w * ws);
    } else {
      ot = o;
    }
    *(ushort4*)&T[hrow][cc4] = ot;
  }
  *(float4*)&P[hh][cc4] = part;
  __syncthreads();
  if (tid < 64) {
    float sum = 0.f;
    #pragma unroll
    for (int i = 0; i < 16; ++i) sum += P[i][tid];
    pbias[(size_t)h1 * B * L + (size_t)b * L + c0 + tid] = sum;
  }
  #pragma unroll
  for (int it = 0; it < 4; ++it) {
    int lin = it * 256 + tid;
    int c = lin >> 4, hc = (lin & 15) * 4;
    ushort4 o;
    o.x = T[hc + 0][c]; o.y = T[hc + 1][c];
    o.z = T[hc + 2][c]; o.w = T[hc + 3][c];
    *(ushort4*)&dT[((size_t)b * L + c0 + c) * H + h1 * 64 + hc] = o;
  }
}

__global__ __launch_bounds__(256) void ktrans_all(
    const float* __restrict__ ctx, const float* __restrict__ qry,
    const float* __restrict__ w, const int* __restrict__ cmask,
    unsigned short* __restrict__ ctx_bf, unsigned short* __restrict__ ctxwT,
    unsigned short* __restrict__ ctxm,
    unsigned short* __restrict__ qry_bf, unsigned short* __restrict__ qryT,
    float* __restrict__ pct, float* __restrict__ pqt,
    float* __restrict__ out) {
  __shared__ unsigned short T[64][72];
  __shared__ float P[16][64];
  const int h1 = blockIdx.y, b = blockIdx.z, tid = threadIdx.x;
  const int bx = blockIdx.x;
  if (bx < CL / 64) {
    ktrans_body<CL, true, true, true>(ctx, w + H, w + 2 * H, cmask,
                                      ctx_bf, ctxwT, ctxm, pct, out,
                                      bx, h1, b, tid, T, P);
  } else {
    ktrans_body<QL, false, false, false>(qry, w, w, nullptr,
                                         qry_bf, qryT, nullptr, pqt, nullptr,
                                         bx - CL / 64, h1, b, tid, T, P);
  }
}

// ---------------- K2: MFMA score + shifted exp; emit eu[q][c] (RAW),
// rsum[b][c] (qmasked row sums), Lpart (cmasked col partial sums). 1 barrier.
__global__ __launch_bounds__(512) void k2_score3(
    const unsigned short* __restrict__ ctxwT, const unsigned short* __restrict__ qryT,
    const float* __restrict__ pct, const float* __restrict__ pqt,
    const int* __restrict__ cmask, const int* __restrict__ qmask,
    unsigned short* __restrict__ eu,
    float* __restrict__ rsum_g, float* __restrict__ Lpart) {
  __shared__ unsigned short t2[256 * 40];   // [256 q][40 c] RAW exp(s-SHIFT)
  __shared__ float stats[32][8];
  __shared__ float cmf[32];
  const int wg = blockIdx.x;
  const int b = wg & (B - 1);          // b innermost -> XCD locality for qryT
  const int cblk = wg >> 4;
  const int c0 = cblk * 32;
  const int tid = threadIdx.x;
  const int w = tid >> 6;
  const int l = tid & 63;
  const int lr = l & 31, hi = l >> 5;
  const int q0 = w * 32;
  const int c = c0 + lr;

  if (tid < 32) cmf[tid] = cmask[b * CL + c0 + tid] > 0 ? 1.f : 0.f;

  // score MFMA: A = qryT rows (M=q), B = ctxwT rows (N=c), K=H=128
  const unsigned short* ap = qryT + ((size_t)b * QL + q0 + lr) * H + hi * 8;
  const unsigned short* bp = ctxwT + ((size_t)b * CL + c) * H + hi * 8;
  f32x16 acc = {};
  #pragma unroll
  for (int k = 0; k < H; k += 16) {
    bf16x8 af = *(const bf16x8*)(ap + k);
    bf16x8 bf_ = *(const bf16x8*)(bp + k);
    acc = __builtin_amdgcn_mfma_f32_32x32x16_bf16(af, bf_, acc, 0, 0, 0);
  }

  const float ct = pct[b * CL + c] + pct[B * CL + b * CL + c];

  float rs = 0.f;    // qmasked row-sum contribution for column c
  #pragma unroll
  for (int g = 0; g < 4; ++g) {
    const int qbase = q0 + 4 * hi + 8 * g;
    float4 qa = *(const float4*)&pqt[b * QL + qbase];
    float4 qb = *(const float4*)&pqt[B * QL + b * QL + qbase];
    int4 m4 = *(const int4*)&qmask[b * QL + qbase];
    float e0 = __expf(acc[4 * g + 0] + ct + qa.x + qb.x - SHIFT);
    float e1 = __expf(acc[4 * g + 1] + ct + qa.y + qb.y - SHIFT);
    float e2 = __expf(acc[4 * g + 2] + ct + qa.z + qb.z - SHIFT);
    float e3 = __expf(acc[4 * g + 3] + ct + qa.w + qb.w - SHIFT);
    rs += (m4.x > 0 ? e0 : 0.f) + (m4.y > 0 ? e1 : 0.f) +
          (m4.z > 0 ? e2 : 0.f) + (m4.w > 0 ? e3 : 0.f);
    t2[(qbase + 0) * 40 + lr] = f2bf(e0);
    t2[(qbase + 1) * 40 + lr] = f2bf(e1);
    t2[(qbase + 2) * 40 + lr] = f2bf(e2);
    t2[(qbase + 3) * 40 + lr] = f2bf(e3);
  }
  rs += __shfl_xor(rs, 32);
  if (hi == 0) stats[lr][w] = rs;
  __syncthreads();

  // epilogue (unordered): rsum, eu copy-out + cmasked Lpart
  if (tid < 32) {
    float s = 0.f;
    #pragma unroll
    for (int ww = 0; ww < 8; ++ww) s += stats[tid][ww];
    rsum_g[b * CL + c0 + tid] = s;
  }
  {
    const int q = tid >> 1, co = (tid & 1) * 16;
    bf16x8 v0 = *(const bf16x8*)&t2[q * 40 + co];
    bf16x8 v1 = *(const bf16x8*)&t2[q * 40 + co + 8];
    float cs = 0.f;
    #pragma unroll
    for (int i2 = 0; i2 < 8; ++i2) {
      cs += bf2f((unsigned short)v0[i2]) * cmf[co + i2];
      cs += bf2f((unsigned short)v1[i2]) * cmf[co + 8 + i2];
    }
    cs += __shfl_xor(cs, 1);
    unsigned short* op = eu + ((size_t)b * QL + q) * CL + c0 + co;
    *(bf16x8*)op = v0;
    *(bf16x8*)(op + 8) = v1;
    if ((tid & 1) == 0) Lpart[((size_t)b * 64 + cblk) * QL + q] = cs;
  }
}

// ---------------- K5: MFMA tpart = sum_c eu[q,c]*ctxm[h,c] (cmask in ctxm) ----
__global__ __launch_bounds__(256, 4) void k5_tpart(
    const unsigned short* __restrict__ eu,
    const unsigned short* __restrict__ ctxm,
    unsigned short* __restrict__ tpart) {
  const int wg = blockIdx.x;
  const int b = wg & (B - 1);
  const int seg = (wg >> 4) & (SPLITK5 - 1);
  const int q0 = (wg >> 7) * 32;
  const int w = threadIdx.x >> 6, l = threadIdx.x & 63;
  const int h0 = w * 32;
  const int lr = l & 31, lg = l >> 5;
  const unsigned short* ap = eu + ((size_t)b * QL + q0 + lr) * CL + seg * K5SEG + lg * 8;
  const unsigned short* bp = ctxm + ((size_t)b * H + h0 + lr) * CL + seg * K5SEG + lg * 8;
  f32x16 acc = {};
  #pragma unroll
  for (int k = 0; k < K5SEG; k += 16) {
    bf16x8 af = *(const bf16x8*)(ap + k);
    bf16x8 bfr = *(const bf16x8*)(bp + k);
    acc = __builtin_amdgcn_mfma_f32_32x32x16_bf16(af, bfr, acc, 0, 0, 0);
  }
  unsigned short* tp = tpart + (size_t)(seg * B + b) * QL * H;
  #pragma unroll
  for (int r = 0; r < 16; ++r) {
    int qrow = (r & 3) + 8 * (r >> 2) + 4 * lg;
    tp[(size_t)(q0 + qrow) * H + h0 + lr] = f2bf(acc[r]);
  }
}

// ---------------- K5b: cinv from Lpart + reduce tpart, write tT_bf[b][h][q] ----
__global__ __launch_bounds__(256) void k5b_treduce(
    const unsigned short* __restrict__ tpart, const float* __restrict__ Lpart,
    unsigned short* __restrict__ tTbf) {
  __shared__ unsigned short lds[32 * 66];
  __shared__ float csum[4][64];
  __shared__ float cinv_s[64];
  const int q0 = blockIdx.x * 64, h0 = blockIdx.y * 32, b = blockIdx.z;
  const int tid = threadIdx.x;
  {
    const int qq = tid & 63, part = tid >> 6;
    float Ls = 0.f;
    #pragma unroll
    for (int k = 0; k < 16; ++k)
      Ls += Lpart[((size_t)b * 64 + part * 16 + k) * QL + q0 + qq];
    csum[part][qq] = Ls;
  }
  __syncthreads();
  if (tid < 64)
    cinv_s[tid] = 1.0f / (csum[0][tid] + csum[1][tid] + csum[2][tid] + csum[3][tid]);
  __syncthreads();
  for (int lin = tid; lin < 64 * 32; lin += 256) {
    int q = lin >> 5, h = lin & 31;
    float v = 0.f;
    #pragma unroll
    for (int sgt = 0; sgt < SPLITK5; ++sgt)
      v += bf2f(tpart[((size_t)(sgt * B + b) * QL + q0 + q) * H + h0 + h]);
    lds[h * 66 + q] = f2bf(v * cinv_s[q]);
  }
  __syncthreads();
  for (int lin = tid; lin < 32 * 64; lin += 256) {
    int h = lin >> 6, q = lin & 63;
    tTbf[((size_t)b * H + h0 + h) * QL + q0 + q] = lds[h * 66 + q];
  }
}

// q-index swizzle inside Ps rows: spreads transposed b16 writes across banks,
// preserves 8-element contiguity (XOR by multiple of 8) for b128 reads.
__device__ __forceinline__ int qswz(int q, int c) {
  return q ^ (((c >> 3) & 7) << 3);
}

// ---------------- KB: dual-GEMM from eu (transpose-staged, qmask folded) ----
// grid 1D (CL/64)*B, b innermost; block 512 (8 waves).
__global__ __launch_bounds__(512) void kb_out(
    const unsigned short* __restrict__ eu,
    const unsigned short* __restrict__ qrybf, const unsigned short* __restrict__ tTbf,
    const unsigned short* __restrict__ ctxbf, const float* __restrict__ rsum_g,
    const int* __restrict__ qmask, float* __restrict__ out) {
  __shared__ unsigned short Ps[64 * 264];   // [64 c][264 q] qmasked P, q-swizzled
  const int wg = blockIdx.x;
  const int b = wg & (B - 1);
  const int c0 = (wg >> 4) * 64;
  const int tid = threadIdx.x;
  const int w = tid >> 6, l = tid & 63;
  const int lr = l & 31, hi = l >> 5;
  const int h0 = (w & 3) * 32;
  const int ch = (w >> 2) * 32;
  const int c = c0 + ch + lr;

  // stage + transpose: eu[q][c0..c0+64] -> Ps[c][qswz(q,c)], qmask per row
  #pragma unroll
  for (int p = 0; p < 4; ++p) {
    const int lin = p * 512 + tid;          // (q, c-octet)
    const int q = lin >> 3, co8 = (lin & 7) * 8;
    bf16x8 v = *(const bf16x8*)&eu[((size_t)b * QL + q) * CL + c0 + co8];
    const bool qm = qmask[b * QL + q] > 0;
    #pragma unroll
    for (int i = 0; i < 8; ++i) {
      const int cc = co8 + i;
      Ps[cc * 264 + qswz(q, cc)] = qm ? (unsigned short)v[i] : (unsigned short)0;
    }
  }

  const float rinv = 1.0f / rsum_g[b * CL + c];

  // epilogue ctx values (overlap with staging)
  unsigned short cvu[16];
  {
    const unsigned short* cvp = ctxbf + (size_t)b * H * CL + c;
    #pragma unroll
    for (int r = 0; r < 16; ++r) {
      const int h = h0 + (r & 3) + 8 * (r >> 2) + 4 * hi;
      cvu[r] = cvp[(size_t)h * CL];
    }
  }
  __syncthreads();

  // dual GEMM: aT[h,c] = sum_q qry[h,q]*P[c,q]; bT[h,c] = sum_q tT[h,q]*P[c,q]
  const unsigned short* a1p = qrybf + ((size_t)b * H + h0 + lr) * QL + hi * 8;
  const unsigned short* a2p = tTbf + ((size_t)b * H + h0 + lr) * QL + hi * 8;
  const int crow = ch + lr;
  f32x16 accA = {}, accB = {};
  #pragma unroll
  for (int kc = 0; kc < 16; ++kc) {
    bf16x8 pb = *(const bf16x8*)&Ps[crow * 264 + qswz(kc * 16 + hi * 8, crow)];
    bf16x8 a1 = *(const bf16x8*)(a1p + kc * 16);
    bf16x8 a2 = *(const bf16x8*)(a2p + kc * 16);
    accA = __builtin_amdgcn_mfma_f32_32x32x16_bf16(a1, pb, accA, 0, 0, 0);
    accB = __builtin_amdgcn_mfma_f32_32x32x16_bf16(a2, pb, accB, 0, 0, 0);
  }
  float* ob = out + (size_t)b * 4 * H * CL;
  #pragma unroll
  for (int r = 0; r < 16; ++r) {
    const int h = h0 + (r & 3) + 8 * (r >> 2) + 4 * hi;
    const float cv = bf2f(cvu[r]);
    const float av = accA[r] * rinv;
    const float bv = accB[r] * rinv;
    __builtin_nontemporal_store(av, &ob[(size_t)(H + h) * CL + c]);
    __builtin_nontemporal_store(cv * av, &ob[(size_t)(2 * H + h) * CL + c]);
    __builtin_nontemporal_store(cv * bv, &ob[(size_t)(3 * H + h) * CL + c]);
  }
}

extern "C" void kernel_launch(void* const* d_in, const int* in_sizes, int n_in,
                              void* d_out, int out_size, void* d_ws, size_t ws_size,
                              hipStream_t stream) {
  const float* context  = (const float*)d_in[0];
  const float* question = (const float*)d_in[1];
  const int*   c_mask   = (const int*)d_in[2];
  const int*   q_mask   = (const int*)d_in[3];
  const float* w        = (const float*)d_in[4];
  float* out = (float*)d_out;

  char* ws = (char*)d_ws;
  size_t off = 0;
  auto alloc = [&](size_t bytes) -> void* {
    void* p = ws + off;
    off += (bytes + 255) & ~(size_t)255;
    return p;
  };
  unsigned short* ctx_bf = (unsigned short*)alloc((size_t)B * H * CL * 2);    // 8.4 MB
  unsigned short* ctxwT  = (unsigned short*)alloc((size_t)B * CL * H * 2);    // 8.4 MB
  unsigned short* ctxm   = (unsigned short*)alloc((size_t)B * H * CL * 2);    // 8.4 MB
  unsigned short* qry_bf = (unsigned short*)alloc((size_t)B * H * QL * 2);    // 1.05 MB
  unsigned short* qryT   = (unsigned short*)alloc((size_t)B * QL * H * 2);    // 1.05 MB
  unsigned short* eu     = (unsigned short*)alloc((size_t)B * QL * CL * 2);   // 16.8 MB
  unsigned short* tpart  = (unsigned short*)alloc((size_t)SPLITK5 * B * QL * H * 2); // 8.4 MB
  unsigned short* tT_bf  = (unsigned short*)alloc((size_t)B * H * QL * 2);    // 1.05 MB
  float* pct   = (float*)alloc((size_t)2 * B * CL * sizeof(float));
  float* pqt   = (float*)alloc((size_t)2 * B * QL * sizeof(float));
  float* rsum_ = (float*)alloc((size_t)B * CL * sizeof(float));
  float* Lpart = (float*)alloc((size_t)B * 64 * QL * sizeof(float));          // 1 MB

  ktrans_all<<<dim3(CL / 64 + QL / 64, H / 64, B), dim3(256), 0, stream>>>(
      context, question, w, c_mask, ctx_bf, ctxwT, ctxm, qry_bf, qryT,
      pct, pqt, out);

  k2_score3<<<dim3((CL / 32) * B), dim3(512), 0, stream>>>(
      ctxwT, qryT, pct, pqt, c_mask, q_mask, eu, rsum_, Lpart);

  k5_tpart<<<dim3((QL / 32) * SPLITK5 * B), dim3(256), 0, stream>>>(
      eu, ctxm, tpart);

  k5b_treduce<<<dim3(QL / 64, H / 32, B), dim3(256), 0, stream>>>(
      tpart, Lpart, tT_bf);

  kb_out<<<dim3((CL / 64) * B), dim3(512), 0, stream>>>(
      eu, qry_bf, tT_bf, ctx_bf, rsum_, q_mask, out);
}

// Round 13
// 85.250 us; speedup vs baseline: 1.0864x; 1.0201x over previous
//
#include <hip/hip_runtime.h>

typedef short bf16x8 __attribute__((ext_vector_type(8)));   // 8 bf16 = 4 VGPRs
typedef float f32x16 __attribute__((ext_vector_type(16)));  // MFMA 32x32 acc
typedef float f32x4  __attribute__((ext_vector_type(4)));
typedef unsigned int u32x4 __attribute__((ext_vector_type(4)));

constexpr int B  = 16;
constexpr int H  = 128;
constexpr int CL = 2048;
constexpr int QL = 256;
constexpr int SPLITK5 = 8;
constexpr int K5SEG = CL / SPLITK5;   // 256
constexpr float SHIFT = 8.0f;         // exp shift (overflow-safe, |s| ~ O(6))

__device__ __forceinline__ unsigned short f2bf(float x) {
  unsigned u = __float_as_uint(x);
  u += 0x7fffu + ((u >> 16) & 1u);   // round-to-nearest-even
  return (unsigned short)(u >> 16);
}
__device__ __forceinline__ float bf2f(unsigned short u) {
  return __uint_as_float((unsigned)u << 16);
}

// ---------------- KT: fp32 -> bf16 linear + transposed copies + bias partials ----
// ctx path additionally writes output group 0 (exact fp32 copy, NT stores).
template<int L, bool SCALE, bool WOUT>
__device__ __forceinline__ void ktrans_body(
    const float* __restrict__ src, const float* __restrict__ wbias,
    const float* __restrict__ wscale,
    unsigned short* __restrict__ dlin, unsigned short* __restrict__ dT,
    float* __restrict__ pbias, float* __restrict__ outg0,
    int bxl, int h1, int b, int tid,
    unsigned short (*T)[72], float (*P)[64]) {
  const int c0 = bxl * 64;
  const int hh = tid >> 4;
  const int cc4 = (tid & 15) * 4;
  float4 part = make_float4(0.f, 0.f, 0.f, 0.f);
  #pragma unroll
  for (int it = 0; it < 4; ++it) {
    const int hrow = it * 16 + hh;
    const int h = h1 * 64 + hrow;
    float4 v = *(const float4*)&src[((size_t)b * H + h) * L + c0 + cc4];
    const float wb = wbias[h];
    part.x = fmaf(v.x, wb, part.x); part.y = fmaf(v.y, wb, part.y);
    part.z = fmaf(v.z, wb, part.z); part.w = fmaf(v.w, wb, part.w);
    if (WOUT) {
      f32x4 t;
      t[0] = v.x; t[1] = v.y; t[2] = v.z; t[3] = v.w;
      __builtin_nontemporal_store(
          t, (f32x4*)&outg0[((size_t)b * 4 * H + h) * (size_t)CL + c0 + cc4]);
    }
    ushort4 o;
    o.x = f2bf(v.x); o.y = f2bf(v.y); o.z = f2bf(v.z); o.w = f2bf(v.w);
    *(ushort4*)&dlin[((size_t)b * H + h) * L + c0 + cc4] = o;
    ushort4 ot;
    if (SCALE) {
      const float ws = wscale[h];
      ot.x = f2bf(v.x * ws); ot.y = f2bf(v.y * ws);
      ot.z = f2bf(v.z * ws); ot.w = f2bf(v.w * ws);
    } else {
      ot = o;
    }
    *(ushort4*)&T[hrow][cc4] = ot;
  }
  *(float4*)&P[hh][cc4] = part;
  __syncthreads();
  if (tid < 64) {
    float sum = 0.f;
    #pragma unroll
    for (int i = 0; i < 16; ++i) sum += P[i][tid];
    pbias[(size_t)h1 * B * L + (size_t)b * L + c0 + tid] = sum;
  }
  #pragma unroll
  for (int it = 0; it < 4; ++it) {
    int lin = it * 256 + tid;
    int c = lin >> 4, hc = (lin & 15) * 4;
    ushort4 o;
    o.x = T[hc + 0][c]; o.y = T[hc + 1][c];
    o.z = T[hc + 2][c]; o.w = T[hc + 3][c];
    *(ushort4*)&dT[((size_t)b * L + c0 + c) * H + h1 * 64 + hc] = o;
  }
}

__global__ __launch_bounds__(256) void ktrans_all(
    const float* __restrict__ ctx, const float* __restrict__ qry,
    const float* __restrict__ w,
    unsigned short* __restrict__ ctx_bf, unsigned short* __restrict__ ctxwT,
    unsigned short* __restrict__ qry_bf, unsigned short* __restrict__ qryT,
    float* __restrict__ pct, float* __restrict__ pqt,
    float* __restrict__ out) {
  __shared__ unsigned short T[64][72];
  __shared__ float P[16][64];
  const int h1 = blockIdx.y, b = blockIdx.z, tid = threadIdx.x;
  const int bx = blockIdx.x;
  if (bx < CL / 64) {
    ktrans_body<CL, true, true>(ctx, w + H, w + 2 * H, ctx_bf, ctxwT, pct, out,
                                bx, h1, b, tid, T, P);
  } else {
    ktrans_body<QL, false, false>(qry, w, w, qry_bf, qryT, pqt, nullptr,
                                  bx - CL / 64, h1, b, tid, T, P);
  }
}

// ---------------- K2: MFMA score + shifted exp; emit eu[q][c] = qmask? e : 0,
// rsum[b][c] (row sums of eu), Lpart (cmasked col partial sums). 1 barrier.
__global__ __launch_bounds__(512) void k2_score4(
    const unsigned short* __restrict__ ctxwT, const unsigned short* __restrict__ qryT,
    const float* __restrict__ pct, const float* __restrict__ pqt,
    const int* __restrict__ cmask, const int* __restrict__ qmask,
    unsigned short* __restrict__ eu,
    float* __restrict__ rsum_g, float* __restrict__ Lpart) {
  __shared__ unsigned short t2[256 * 40];   // [256 q][40 c] qmasked exp(s-SHIFT)
  __shared__ float stats[32][8];
  __shared__ float cmf[32];
  const int wg = blockIdx.x;
  const int b = wg & (B - 1);          // b innermost -> XCD locality for qryT
  const int cblk = wg >> 4;
  const int c0 = cblk * 32;
  const int tid = threadIdx.x;
  const int w = tid >> 6;
  const int l = tid & 63;
  const int lr = l & 31, hi = l >> 5;
  const int q0 = w * 32;
  const int c = c0 + lr;

  if (tid < 32) cmf[tid] = cmask[b * CL + c0 + tid] > 0 ? 1.f : 0.f;

  // score MFMA: A = qryT rows (M=q), B = ctxwT rows (N=c), K=H=128
  const unsigned short* ap = qryT + ((size_t)b * QL + q0 + lr) * H + hi * 8;
  const unsigned short* bp = ctxwT + ((size_t)b * CL + c) * H + hi * 8;
  f32x16 acc = {};
  #pragma unroll
  for (int k = 0; k < H; k += 16) {
    bf16x8 af = *(const bf16x8*)(ap + k);
    bf16x8 bf_ = *(const bf16x8*)(bp + k);
    acc = __builtin_amdgcn_mfma_f32_32x32x16_bf16(af, bf_, acc, 0, 0, 0);
  }

  const float ct = pct[b * CL + c] + pct[B * CL + b * CL + c];

  float rs = 0.f;    // row-sum (over q) contribution for column c
  #pragma unroll
  for (int g = 0; g < 4; ++g) {
    const int qbase = q0 + 4 * hi + 8 * g;
    float4 qa = *(const float4*)&pqt[b * QL + qbase];
    float4 qb = *(const float4*)&pqt[B * QL + b * QL + qbase];
    int4 m4 = *(const int4*)&qmask[b * QL + qbase];
    float e0 = m4.x > 0 ? __expf(acc[4 * g + 0] + ct + qa.x + qb.x - SHIFT) : 0.f;
    float e1 = m4.y > 0 ? __expf(acc[4 * g + 1] + ct + qa.y + qb.y - SHIFT) : 0.f;
    float e2 = m4.z > 0 ? __expf(acc[4 * g + 2] + ct + qa.z + qb.z - SHIFT) : 0.f;
    float e3 = m4.w > 0 ? __expf(acc[4 * g + 3] + ct + qa.w + qb.w - SHIFT) : 0.f;
    rs += e0 + e1 + e2 + e3;
    t2[(qbase + 0) * 40 + lr] = f2bf(e0);
    t2[(qbase + 1) * 40 + lr] = f2bf(e1);
    t2[(qbase + 2) * 40 + lr] = f2bf(e2);
    t2[(qbase + 3) * 40 + lr] = f2bf(e3);
  }
  rs += __shfl_xor(rs, 32);
  if (hi == 0) stats[lr][w] = rs;
  __syncthreads();

  // epilogue (unordered): rsum, eu copy-out + cmasked Lpart
  if (tid < 32) {
    float s = 0.f;
    #pragma unroll
    for (int ww = 0; ww < 8; ++ww) s += stats[tid][ww];
    rsum_g[b * CL + c0 + tid] = s;
  }
  {
    const int q = tid >> 1, co = (tid & 1) * 16;
    bf16x8 v0 = *(const bf16x8*)&t2[q * 40 + co];
    bf16x8 v1 = *(const bf16x8*)&t2[q * 40 + co + 8];
    float cs = 0.f;
    #pragma unroll
    for (int i2 = 0; i2 < 8; ++i2) {
      cs += bf2f((unsigned short)v0[i2]) * cmf[co + i2];
      cs += bf2f((unsigned short)v1[i2]) * cmf[co + 8 + i2];
    }
    cs += __shfl_xor(cs, 1);
    unsigned short* op = eu + ((size_t)b * QL + q) * CL + c0 + co;
    *(bf16x8*)op = v0;
    *(bf16x8*)(op + 8) = v1;
    if ((tid & 1) == 0) Lpart[((size_t)b * 64 + cblk) * QL + q] = cs;
  }
}

// ---------------- K5: MFMA tpart = sum_c eu[q,c]*ctx[h,c], cmask via frag AND ----
__global__ __launch_bounds__(256, 4) void k5_tpart(
    const unsigned short* __restrict__ eu,
    const unsigned short* __restrict__ ctxbf,
    const int* __restrict__ cmask,
    unsigned short* __restrict__ tpart) {
  __shared__ unsigned int cmm[K5SEG / 2];   // packed 2x16-bit AND masks per uint
  const int wg = blockIdx.x;
  const int b = wg & (B - 1);
  const int seg = (wg >> 4) & (SPLITK5 - 1);
  const int q0 = (wg >> 7) * 32;
  const int tid = threadIdx.x;
  if (tid < K5SEG / 2) {
    const int cbase = b * CL + seg * K5SEG + tid * 2;
    cmm[tid] = (cmask[cbase] > 0 ? 0xFFFFu : 0u) |
               (cmask[cbase + 1] > 0 ? 0xFFFF0000u : 0u);
  }
  __syncthreads();
  const int w = tid >> 6, l = tid & 63;
  const int h0 = w * 32;
  const int lr = l & 31, lg = l >> 5;
  const unsigned short* ap = eu + ((size_t)b * QL + q0 + lr) * CL + seg * K5SEG + lg * 8;
  const unsigned short* bp = ctxbf + ((size_t)b * H + h0 + lr) * CL + seg * K5SEG + lg * 8;
  f32x16 acc = {};
  #pragma unroll
  for (int k = 0; k < K5SEG; k += 16) {
    bf16x8 af = *(const bf16x8*)(ap + k);
    bf16x8 bfr = *(const bf16x8*)(bp + k);
    u32x4 mm = *(const u32x4*)&cmm[(k >> 1) + lg * 4];
    u32x4 ai = __builtin_bit_cast(u32x4, af);
    ai &= mm;                                 // exact: zero masked-c bf16 lanes
    af = __builtin_bit_cast(bf16x8, ai);
    acc = __builtin_amdgcn_mfma_f32_32x32x16_bf16(af, bfr, acc, 0, 0, 0);
  }
  unsigned short* tp = tpart + (size_t)(seg * B + b) * QL * H;
  #pragma unroll
  for (int r = 0; r < 16; ++r) {
    int qrow = (r & 3) + 8 * (r >> 2) + 4 * lg;
    tp[(size_t)(q0 + qrow) * H + h0 + lr] = f2bf(acc[r]);
  }
}

// ---------------- K5b: cinv from Lpart + reduce tpart, write tT_bf[b][h][q] ----
// grid (QL/64, H/16, B) = 512 blocks.
__global__ __launch_bounds__(256) void k5b_treduce(
    const unsigned short* __restrict__ tpart, const float* __restrict__ Lpart,
    unsigned short* __restrict__ tTbf) {
  __shared__ unsigned short lds[16 * 66];
  __shared__ float csum[4][64];
  __shared__ float cinv_s[64];
  const int q0 = blockIdx.x * 64, h0 = blockIdx.y * 16, b = blockIdx.z;
  const int tid = threadIdx.x;
  {
    const int qq = tid & 63, part = tid >> 6;
    float Ls = 0.f;
    #pragma unroll
    for (int k = 0; k < 16; ++k)
      Ls += Lpart[((size_t)b * 64 + part * 16 + k) * QL + q0 + qq];
    csum[part][qq] = Ls;
  }
  __syncthreads();
  if (tid < 64)
    cinv_s[tid] = 1.0f / (csum[0][tid] + csum[1][tid] + csum[2][tid] + csum[3][tid]);
  __syncthreads();
  for (int lin = tid; lin < 64 * 16; lin += 256) {
    int q = lin >> 4, h = lin & 15;
    float v = 0.f;
    #pragma unroll
    for (int sgt = 0; sgt < SPLITK5; ++sgt)
      v += bf2f(tpart[((size_t)(sgt * B + b) * QL + q0 + q) * H + h0 + h]);
    lds[h * 66 + q] = f2bf(v * cinv_s[q]);
  }
  __syncthreads();
  for (int lin = tid; lin < 16 * 64; lin += 256) {
    int h = lin >> 6, q = lin & 63;
    tTbf[((size_t)b * H + h0 + h) * QL + q0 + q] = lds[h * 66 + q];
  }
}

// q-index swizzle inside Ps rows: spreads transposed b16 writes across banks,
// preserves 8-element contiguity (XOR by multiple of 8) for b128 reads.
__device__ __forceinline__ int qswz(int q, int c) {
  return q ^ (((c >> 3) & 7) << 3);
}

// ---------------- KB: dual-GEMM from eu (transpose-staged; qmask pre-folded) ----
// grid 1D (CL/64)*B, b innermost; block 512 (8 waves).
__global__ __launch_bounds__(512) void kb_out(
    const unsigned short* __restrict__ eu,
    const unsigned short* __restrict__ qrybf, const unsigned short* __restrict__ tTbf,
    const unsigned short* __restrict__ ctxbf, const float* __restrict__ rsum_g,
    float* __restrict__ out) {
  __shared__ unsigned short Ps[64 * 264];   // [64 c][264 q] P-tile, q-swizzled
  const int wg = blockIdx.x;
  const int b = wg & (B - 1);
  const int c0 = (wg >> 4) * 64;
  const int tid = threadIdx.x;
  const int w = tid >> 6, l = tid & 63;
  const int lr = l & 31, hi = l >> 5;
  const int h0 = (w & 3) * 32;
  const int ch = (w >> 2) * 32;
  const int c = c0 + ch + lr;

  // stage + transpose: eu[q][c0..c0+64] -> Ps[c][qswz(q,c)]
  #pragma unroll
  for (int p = 0; p < 4; ++p) {
    const int lin = p * 512 + tid;          // (q, c-octet)
    const int q = lin >> 3, co8 = (lin & 7) * 8;
    bf16x8 v = *(const bf16x8*)&eu[((size_t)b * QL + q) * CL + c0 + co8];
    #pragma unroll
    for (int i = 0; i < 8; ++i) {
      const int cc = co8 + i;
      Ps[cc * 264 + qswz(q, cc)] = (unsigned short)v[i];
    }
  }

  const float rinv = 1.0f / rsum_g[b * CL + c];

  // epilogue ctx values (overlap with staging)
  unsigned short cvu[16];
  {
    const unsigned short* cvp = ctxbf + (size_t)b * H * CL + c;
    #pragma unroll
    for (int r = 0; r < 16; ++r) {
      const int h = h0 + (r & 3) + 8 * (r >> 2) + 4 * hi;
      cvu[r] = cvp[(size_t)h * CL];
    }
  }
  __syncthreads();

  // dual GEMM: aT[h,c] = sum_q qry[h,q]*P[c,q]; bT[h,c] = sum_q tT[h,q]*P[c,q]
  const unsigned short* a1p = qrybf + ((size_t)b * H + h0 + lr) * QL + hi * 8;
  const unsigned short* a2p = tTbf + ((size_t)b * H + h0 + lr) * QL + hi * 8;
  const int crow = ch + lr;
  f32x16 accA = {}, accB = {};
  #pragma unroll
  for (int kc = 0; kc < 16; ++kc) {
    bf16x8 pb = *(const bf16x8*)&Ps[crow * 264 + qswz(kc * 16 + hi * 8, crow)];
    bf16x8 a1 = *(const bf16x8*)(a1p + kc * 16);
    bf16x8 a2 = *(const bf16x8*)(a2p + kc * 16);
    accA = __builtin_amdgcn_mfma_f32_32x32x16_bf16(a1, pb, accA, 0, 0, 0);
    accB = __builtin_amdgcn_mfma_f32_32x32x16_bf16(a2, pb, accB, 0, 0, 0);
  }
  float* ob = out + (size_t)b * 4 * H * CL;
  #pragma unroll
  for (int r = 0; r < 16; ++r) {
    const int h = h0 + (r & 3) + 8 * (r >> 2) + 4 * hi;
    const float cv = bf2f(cvu[r]);
    const float av = accA[r] * rinv;
    const float bv = accB[r] * rinv;
    __builtin_nontemporal_store(av, &ob[(size_t)(H + h) * CL + c]);
    __builtin_nontemporal_store(cv * av, &ob[(size_t)(2 * H + h) * CL + c]);
    __builtin_nontemporal_store(cv * bv, &ob[(size_t)(3 * H + h) * CL + c]);
  }
}

extern "C" void kernel_launch(void* const* d_in, const int* in_sizes, int n_in,
                              void* d_out, int out_size, void* d_ws, size_t ws_size,
                              hipStream_t stream) {
  const float* context  = (const float*)d_in[0];
  const float* question = (const float*)d_in[1];
  const int*   c_mask   = (const int*)d_in[2];
  const int*   q_mask   = (const int*)d_in[3];
  const float* w        = (const float*)d_in[4];
  float* out = (float*)d_out;

  char* ws = (char*)d_ws;
  size_t off = 0;
  auto alloc = [&](size_t bytes) -> void* {
    void* p = ws + off;
    off += (bytes + 255) & ~(size_t)255;
    return p;
  };
  unsigned short* ctx_bf = (unsigned short*)alloc((size_t)B * H * CL * 2);    // 8.4 MB
  unsigned short* ctxwT  = (unsigned short*)alloc((size_t)B * CL * H * 2);    // 8.4 MB
  unsigned short* qry_bf = (unsigned short*)alloc((size_t)B * H * QL * 2);    // 1.05 MB
  unsigned short* qryT   = (unsigned short*)alloc((size_t)B * QL * H * 2);    // 1.05 MB
  unsigned short* eu     = (unsigned short*)alloc((size_t)B * QL * CL * 2);   // 16.8 MB
  unsigned short* tpart  = (unsigned short*)alloc((size_t)SPLITK5 * B * QL * H * 2); // 8.4 MB
  unsigned short* tT_bf  = (unsigned short*)alloc((size_t)B * H * QL * 2);    // 1.05 MB
  float* pct   = (float*)alloc((size_t)2 * B * CL * sizeof(float));
  float* pqt   = (float*)alloc((size_t)2 * B * QL * sizeof(float));
  float* rsum_ = (float*)alloc((size_t)B * CL * sizeof(float));
  float* Lpart = (float*)alloc((size_t)B * 64 * QL * sizeof(float));          // 1 MB

  ktrans_all<<<dim3(CL / 64 + QL / 64, H / 64, B), dim3(256), 0, stream>>>(
      context, question, w, ctx_bf, ctxwT, qry_bf, qryT, pct, pqt, out);

  k2_score4<<<dim3((CL / 32) * B), dim3(512), 0, stream>>>(
      ctxwT, qryT, pct, pqt, c_mask, q_mask, eu, rsum_, Lpart);

  k5_tpart<<<dim3((QL / 32) * SPLITK5 * B), dim3(256), 0, stream>>>(
      eu, ctx_bf, c_mask, tpart);

  k5b_treduce<<<dim3(QL / 64, H / 16, B), dim3(256), 0, stream>>>(
      tpart, Lpart, tT_bf);

  kb_out<<<dim3((CL / 64) * B), dim3(512), 0, stream>>>(
      eu, qry_bf, tT_bf, ctx_bf, rsum_, out);
}

// Round 14
// 84.368 us; speedup vs baseline: 1.0977x; 1.0104x over previous
//
#include <hip/hip_runtime.h>

typedef short bf16x8 __attribute__((ext_vector_type(8)));   // 8 bf16 = 4 VGPRs
typedef float f32x16 __attribute__((ext_vector_type(16)));  // MFMA 32x32 acc
typedef float f32x4  __attribute__((ext_vector_type(4)));
typedef unsigned int u32x4 __attribute__((ext_vector_type(4)));

constexpr int B  = 16;
constexpr int H  = 128;
constexpr int CL = 2048;
constexpr int QL = 256;
constexpr int SPLITK5 = 8;
constexpr int K5SEG = CL / SPLITK5;   // 256
constexpr float SHIFT = 8.0f;         // exp shift (overflow-safe, |s| ~ O(6))

__device__ __forceinline__ unsigned short f2bf(float x) {
  unsigned u = __float_as_uint(x);
  u += 0x7fffu + ((u >> 16) & 1u);   // round-to-nearest-even
  return (unsigned short)(u >> 16);
}
__device__ __forceinline__ float bf2f(unsigned short u) {
  return __uint_as_float((unsigned)u << 16);
}

// ---------------- KT: fp32 -> bf16 linear + transposed copies + bias partials ----
// ctx path additionally writes output group 0 (exact fp32 copy, NT stores).
template<int L, bool SCALE, bool WOUT>
__device__ __forceinline__ void ktrans_body(
    const float* __restrict__ src, const float* __restrict__ wbias,
    const float* __restrict__ wscale,
    unsigned short* __restrict__ dlin, unsigned short* __restrict__ dT,
    float* __restrict__ pbias, float* __restrict__ outg0,
    int bxl, int h1, int b, int tid,
    unsigned short (*T)[72], float (*P)[64]) {
  const int c0 = bxl * 64;
  const int hh = tid >> 4;
  const int cc4 = (tid & 15) * 4;
  float4 part = make_float4(0.f, 0.f, 0.f, 0.f);
  #pragma unroll
  for (int it = 0; it < 4; ++it) {
    const int hrow = it * 16 + hh;
    const int h = h1 * 64 + hrow;
    float4 v = *(const float4*)&src[((size_t)b * H + h) * L + c0 + cc4];
    const float wb = wbias[h];
    part.x = fmaf(v.x, wb, part.x); part.y = fmaf(v.y, wb, part.y);
    part.z = fmaf(v.z, wb, part.z); part.w = fmaf(v.w, wb, part.w);
    if (WOUT) {
      f32x4 t;
      t[0] = v.x; t[1] = v.y; t[2] = v.z; t[3] = v.w;
      __builtin_nontemporal_store(
          t, (f32x4*)&outg0[((size_t)b * 4 * H + h) * (size_t)CL + c0 + cc4]);
    }
    ushort4 o;
    o.x = f2bf(v.x); o.y = f2bf(v.y); o.z = f2bf(v.z); o.w = f2bf(v.w);
    *(ushort4*)&dlin[((size_t)b * H + h) * L + c0 + cc4] = o;
    ushort4 ot;
    if (SCALE) {
      const float ws = wscale[h];
      ot.x = f2bf(v.x * ws); ot.y = f2bf(v.y * ws);
      ot.z = f2bf(v.z * ws); ot.w = f2bf(v.w * ws);
    } else {
      ot = o;
    }
    *(ushort4*)&T[hrow][cc4] = ot;
  }
  *(float4*)&P[hh][cc4] = part;
  __syncthreads();
  if (tid < 64) {
    float sum = 0.f;
    #pragma unroll
    for (int i = 0; i < 16; ++i) sum += P[i][tid];
    pbias[(size_t)h1 * B * L + (size_t)b * L + c0 + tid] = sum;
  }
  #pragma unroll
  for (int it = 0; it < 4; ++it) {
    int lin = it * 256 + tid;
    int c = lin >> 4, hc = (lin & 15) * 4;
    ushort4 o;
    o.x = T[hc + 0][c]; o.y = T[hc + 1][c];
    o.z = T[hc + 2][c]; o.w = T[hc + 3][c];
    *(ushort4*)&dT[((size_t)b * L + c0 + c) * H + h1 * 64 + hc] = o;
  }
}

__global__ __launch_bounds__(256) void ktrans_all(
    const float* __restrict__ ctx, const float* __restrict__ qry,
    const float* __restrict__ w,
    unsigned short* __restrict__ ctx_bf, unsigned short* __restrict__ ctxwT,
    unsigned short* __restrict__ qry_bf, unsigned short* __restrict__ qryT,
    float* __restrict__ pct, float* __restrict__ pqt,
    float* __restrict__ out) {
  __shared__ unsigned short T[64][72];
  __shared__ float P[16][64];
  const int h1 = blockIdx.y, b = blockIdx.z, tid = threadIdx.x;
  const int bx = blockIdx.x;
  if (bx < CL / 64) {
    ktrans_body<CL, true, true>(ctx, w + H, w + 2 * H, ctx_bf, ctxwT, pct, out,
                                bx, h1, b, tid, T, P);
  } else {
    ktrans_body<QL, false, false>(qry, w, w, qry_bf, qryT, pqt, nullptr,
                                  bx - CL / 64, h1, b, tid, T, P);
  }
}

// ---------------- K2: MFMA score + shifted exp; emit eu[q][c] = qmask? e : 0,
// rsum[b][c], Lpart (cmasked col partial sums). Wave-local copy-out (no barrier
// on the fat path; t2 rows of wave w are written only by wave w).
__global__ __launch_bounds__(512) void k2_score5(
    const unsigned short* __restrict__ ctxwT, const unsigned short* __restrict__ qryT,
    const float* __restrict__ pct, const float* __restrict__ pqt,
    const int* __restrict__ cmask, const int* __restrict__ qmask,
    unsigned short* __restrict__ eu,
    float* __restrict__ rsum_g, float* __restrict__ Lpart) {
  __shared__ unsigned short t2[256 * 40];   // [256 q][40 c] qmasked exp(s-SHIFT)
  __shared__ float stats[32][8];
  __shared__ float cmf[32];
  const int wg = blockIdx.x;
  const int b = wg & (B - 1);          // b innermost -> XCD locality for qryT
  const int cblk = wg >> 4;
  const int c0 = cblk * 32;
  const int tid = threadIdx.x;
  const int w = tid >> 6;
  const int l = tid & 63;
  const int lr = l & 31, hi = l >> 5;
  const int q0 = w * 32;
  const int c = c0 + lr;

  // per-wave idempotent cmf fill (same values from every wave; wave-local read)
  if (l < 32) cmf[l] = cmask[b * CL + c0 + l] > 0 ? 1.f : 0.f;

  // score MFMA: A = qryT rows (M=q), B = ctxwT rows (N=c), K=H=128
  const unsigned short* ap = qryT + ((size_t)b * QL + q0 + lr) * H + hi * 8;
  const unsigned short* bp = ctxwT + ((size_t)b * CL + c) * H + hi * 8;
  f32x16 acc = {};
  #pragma unroll
  for (int k = 0; k < H; k += 16) {
    bf16x8 af = *(const bf16x8*)(ap + k);
    bf16x8 bf_ = *(const bf16x8*)(bp + k);
    acc = __builtin_amdgcn_mfma_f32_32x32x16_bf16(af, bf_, acc, 0, 0, 0);
  }

  const float ct = pct[b * CL + c] + pct[B * CL + b * CL + c];

  float rs = 0.f;    // row-sum (over q) contribution for column c
  #pragma unroll
  for (int g = 0; g < 4; ++g) {
    const int qbase = q0 + 4 * hi + 8 * g;
    float4 qa = *(const float4*)&pqt[b * QL + qbase];
    float4 qb = *(const float4*)&pqt[B * QL + b * QL + qbase];
    int4 m4 = *(const int4*)&qmask[b * QL + qbase];
    float e0 = m4.x > 0 ? __expf(acc[4 * g + 0] + ct + qa.x + qb.x - SHIFT) : 0.f;
    float e1 = m4.y > 0 ? __expf(acc[4 * g + 1] + ct + qa.y + qb.y - SHIFT) : 0.f;
    float e2 = m4.z > 0 ? __expf(acc[4 * g + 2] + ct + qa.z + qb.z - SHIFT) : 0.f;
    float e3 = m4.w > 0 ? __expf(acc[4 * g + 3] + ct + qa.w + qb.w - SHIFT) : 0.f;
    rs += e0 + e1 + e2 + e3;
    t2[(qbase + 0) * 40 + lr] = f2bf(e0);
    t2[(qbase + 1) * 40 + lr] = f2bf(e1);
    t2[(qbase + 2) * 40 + lr] = f2bf(e2);
    t2[(qbase + 3) * 40 + lr] = f2bf(e3);
  }
  rs += __shfl_xor(rs, 32);
  if (hi == 0) stats[lr][w] = rs;

  // wave-local eu copy-out + Lpart: this wave reads only rows it wrote.
  __threadfence_block();   // drain LDS writes (lgkmcnt) before wave-local reads
  {
    const int q = q0 + (l >> 1), co = (l & 1) * 16;
    bf16x8 v0 = *(const bf16x8*)&t2[q * 40 + co];
    bf16x8 v1 = *(const bf16x8*)&t2[q * 40 + co + 8];
    float cs = 0.f;
    #pragma unroll
    for (int i2 = 0; i2 < 8; ++i2) {
      cs += bf2f((unsigned short)v0[i2]) * cmf[co + i2];
      cs += bf2f((unsigned short)v1[i2]) * cmf[co + 8 + i2];
    }
    cs += __shfl_xor(cs, 1);
    unsigned short* op = eu + ((size_t)b * QL + q) * CL + c0 + co;
    *(bf16x8*)op = v0;
    *(bf16x8*)(op + 8) = v1;
    if ((l & 1) == 0) Lpart[((size_t)b * 64 + cblk) * QL + q] = cs;
  }
  __syncthreads();   // only gates the tiny cross-wave rsum reduce
  if (tid < 32) {
    float s = 0.f;
    #pragma unroll
    for (int ww = 0; ww < 8; ++ww) s += stats[tid][ww];
    rsum_g[b * CL + c0 + tid] = s;
  }
}

// ---------------- K5: MFMA tpart = sum_c eu[q,c]*ctx[h,c], cmask via frag AND ----
__global__ __launch_bounds__(256, 4) void k5_tpart(
    const unsigned short* __restrict__ eu,
    const unsigned short* __restrict__ ctxbf,
    const int* __restrict__ cmask,
    unsigned short* __restrict__ tpart) {
  __shared__ unsigned int cmm[K5SEG / 2];   // packed 2x16-bit AND masks per uint
  const int wg = blockIdx.x;
  const int b = wg & (B - 1);
  const int seg = (wg >> 4) & (SPLITK5 - 1);
  const int q0 = (wg >> 7) * 32;
  const int tid = threadIdx.x;
  if (tid < K5SEG / 2) {
    const int cbase = b * CL + seg * K5SEG + tid * 2;
    cmm[tid] = (cmask[cbase] > 0 ? 0xFFFFu : 0u) |
               (cmask[cbase + 1] > 0 ? 0xFFFF0000u : 0u);
  }
  __syncthreads();
  const int w = tid >> 6, l = tid & 63;
  const int h0 = w * 32;
  const int lr = l & 31, lg = l >> 5;
  const unsigned short* ap = eu + ((size_t)b * QL + q0 + lr) * CL + seg * K5SEG + lg * 8;
  const unsigned short* bp = ctxbf + ((size_t)b * H + h0 + lr) * CL + seg * K5SEG + lg * 8;
  f32x16 acc = {};
  #pragma unroll
  for (int k = 0; k < K5SEG; k += 16) {
    bf16x8 af = *(const bf16x8*)(ap + k);
    bf16x8 bfr = *(const bf16x8*)(bp + k);
    u32x4 mm = *(const u32x4*)&cmm[(k >> 1) + lg * 4];
    u32x4 ai = __builtin_bit_cast(u32x4, af);
    ai &= mm;                                 // exact: zero masked-c bf16 lanes
    af = __builtin_bit_cast(bf16x8, ai);
    acc = __builtin_amdgcn_mfma_f32_32x32x16_bf16(af, bfr, acc, 0, 0, 0);
  }
  unsigned short* tp = tpart + (size_t)(seg * B + b) * QL * H;
  #pragma unroll
  for (int r = 0; r < 16; ++r) {
    int qrow = (r & 3) + 8 * (r >> 2) + 4 * lg;
    tp[(size_t)(q0 + qrow) * H + h0 + lr] = f2bf(acc[r]);
  }
}

// ---------------- K5b: cinv from Lpart + reduce tpart, write tT_bf[b][h][q] ----
// grid (QL/64, H/16, B) = 512 blocks.
__global__ __launch_bounds__(256) void k5b_treduce(
    const unsigned short* __restrict__ tpart, const float* __restrict__ Lpart,
    unsigned short* __restrict__ tTbf) {
  __shared__ unsigned short lds[16 * 66];
  __shared__ float csum[4][64];
  __shared__ float cinv_s[64];
  const int q0 = blockIdx.x * 64, h0 = blockIdx.y * 16, b = blockIdx.z;
  const int tid = threadIdx.x;
  {
    const int qq = tid & 63, part = tid >> 6;
    float Ls = 0.f;
    #pragma unroll
    for (int k = 0; k < 16; ++k)
      Ls += Lpart[((size_t)b * 64 + part * 16 + k) * QL + q0 + qq];
    csum[part][qq] = Ls;
  }
  __syncthreads();
  if (tid < 64)
    cinv_s[tid] = 1.0f / (csum[0][tid] + csum[1][tid] + csum[2][tid] + csum[3][tid]);
  __syncthreads();
  for (int lin = tid; lin < 64 * 16; lin += 256) {
    int q = lin >> 4, h = lin & 15;
    float v = 0.f;
    #pragma unroll
    for (int sgt = 0; sgt < SPLITK5; ++sgt)
      v += bf2f(tpart[((size_t)(sgt * B + b) * QL + q0 + q) * H + h0 + h]);
    lds[h * 66 + q] = f2bf(v * cinv_s[q]);
  }
  __syncthreads();
  for (int lin = tid; lin < 16 * 64; lin += 256) {
    int h = lin >> 6, q = lin & 63;
    tTbf[((size_t)b * H + h0 + h) * QL + q0 + q] = lds[h * 66 + q];
  }
}

// q-index swizzle inside Ps rows: spreads transposed b16 writes across banks,
// preserves 8-element contiguity (XOR by multiple of 8) for b128 reads.
// Only touches q-bits 3..5, so q-halves [0,128)/[128,256) are preserved.
__device__ __forceinline__ int qswz(int q, int c) {
  return q ^ (((c >> 3) & 7) << 3);
}

// ---------------- KB: dual-GEMM from eu, q-half software pipeline ----
// grid 1D (CL/64)*B, b innermost; block 512 (8 waves).
// stage q<128 -> sync -> GEMM kc 0..7 (half-1 loads in flight) -> write half-1
// (disjoint LDS) -> sync -> GEMM kc 8..15 -> NT stores.
__global__ __launch_bounds__(512) void kb_out(
    const unsigned short* __restrict__ eu,
    const unsigned short* __restrict__ qrybf, const unsigned short* __restrict__ tTbf,
    const unsigned short* __restrict__ ctxbf, const float* __restrict__ rsum_g,
    float* __restrict__ out) {
  __shared__ unsigned short Ps[64 * 264];   // [64 c][264 q] P-tile, q-swizzled
  const int wg = blockIdx.x;
  const int b = wg & (B - 1);
  const int c0 = (wg >> 4) * 64;
  const int tid = threadIdx.x;
  const int w = tid >> 6, l = tid & 63;
  const int lr = l & 31, hi = l >> 5;
  const int h0 = (w & 3) * 32;
  const int ch = (w >> 2) * 32;
  const int c = c0 + ch + lr;

  // stage half 0: q in [0,128)
  #pragma unroll
  for (int p = 0; p < 2; ++p) {
    const int lin = p * 512 + tid;          // (q, c-octet)
    const int q = lin >> 3, co8 = (lin & 7) * 8;
    bf16x8 v = *(const bf16x8*)&eu[((size_t)b * QL + q) * CL + c0 + co8];
    #pragma unroll
    for (int i = 0; i < 8; ++i) {
      const int cc = co8 + i;
      Ps[cc * 264 + qswz(q, cc)] = (unsigned short)v[i];
    }
  }

  // epilogue ctx values + rinv (overlap with staging)
  unsigned short cvu[16];
  {
    const unsigned short* cvp = ctxbf + (size_t)b * H * CL + c;
    #pragma unroll
    for (int r = 0; r < 16; ++r) {
      const int h = h0 + (r & 3) + 8 * (r >> 2) + 4 * hi;
      cvu[r] = cvp[(size_t)h * CL];
    }
  }
  const float rinv = 1.0f / rsum_g[b * CL + c];

  // issue half-1 loads now; vmcnt-wait lands after GEMM half 0
  bf16x8 st0, st1;
  const int lin2 = 2 * 512 + tid, lin3 = 3 * 512 + tid;
  {
    const int q = lin2 >> 3, co8 = (lin2 & 7) * 8;
    st0 = *(const bf16x8*)&eu[((size_t)b * QL + q) * CL + c0 + co8];
  }
  {
    const int q = lin3 >> 3, co8 = (lin3 & 7) * 8;
    st1 = *(const bf16x8*)&eu[((size_t)b * QL + q) * CL + c0 + co8];
  }
  __syncthreads();   // half-0 visible

  const unsigned short* a1p = qrybf + ((size_t)b * H + h0 + lr) * QL + hi * 8;
  const unsigned short* a2p = tTbf + ((size_t)b * H + h0 + lr) * QL + hi * 8;
  const int crow = ch + lr;
  f32x16 accA = {}, accB = {};
  #pragma unroll
  for (int kc = 0; kc < 8; ++kc) {
    bf16x8 pb = *(const bf16x8*)&Ps[crow * 264 + qswz(kc * 16 + hi * 8, crow)];
    bf16x8 a1 = *(const bf16x8*)(a1p + kc * 16);
    bf16x8 a2 = *(const bf16x8*)(a2p + kc * 16);
    accA = __builtin_amdgcn_mfma_f32_32x32x16_bf16(a1, pb, accA, 0, 0, 0);
    accB = __builtin_amdgcn_mfma_f32_32x32x16_bf16(a2, pb, accB, 0, 0, 0);
  }

  // write half 1 (disjoint from half 0: qswz preserves halves)
  {
    const int q = lin2 >> 3, co8 = (lin2 & 7) * 8;
    #pragma unroll
    for (int i = 0; i < 8; ++i) {
      const int cc = co8 + i;
      Ps[cc * 264 + qswz(q, cc)] = (unsigned short)st0[i];
    }
  }
  {
    const int q = lin3 >> 3, co8 = (lin3 & 7) * 8;
    #pragma unroll
    for (int i = 0; i < 8; ++i) {
      const int cc = co8 + i;
      Ps[cc * 264 + qswz(q, cc)] = (unsigned short)st1[i];
    }
  }
  __syncthreads();   // half-1 visible

  #pragma unroll
  for (int kc = 8; kc < 16; ++kc) {
    bf16x8 pb = *(const bf16x8*)&Ps[crow * 264 + qswz(kc * 16 + hi * 8, crow)];
    bf16x8 a1 = *(const bf16x8*)(a1p + kc * 16);
    bf16x8 a2 = *(const bf16x8*)(a2p + kc * 16);
    accA = __builtin_amdgcn_mfma_f32_32x32x16_bf16(a1, pb, accA, 0, 0, 0);
    accB = __builtin_amdgcn_mfma_f32_32x32x16_bf16(a2, pb, accB, 0, 0, 0);
  }

  float* ob = out + (size_t)b * 4 * H * CL;
  #pragma unroll
  for (int r = 0; r < 16; ++r) {
    const int h = h0 + (r & 3) + 8 * (r >> 2) + 4 * hi;
    const float cv = bf2f(cvu[r]);
    const float av = accA[r] * rinv;
    const float bv = accB[r] * rinv;
    __builtin_nontemporal_store(av, &ob[(size_t)(H + h) * CL + c]);
    __builtin_nontemporal_store(cv * av, &ob[(size_t)(2 * H + h) * CL + c]);
    __builtin_nontemporal_store(cv * bv, &ob[(size_t)(3 * H + h) * CL + c]);
  }
}

extern "C" void kernel_launch(void* const* d_in, const int* in_sizes, int n_in,
                              void* d_out, int out_size, void* d_ws, size_t ws_size,
                              hipStream_t stream) {
  const float* context  = (const float*)d_in[0];
  const float* question = (const float*)d_in[1];
  const int*   c_mask   = (const int*)d_in[2];
  const int*   q_mask   = (const int*)d_in[3];
  const float* w        = (const float*)d_in[4];
  float* out = (float*)d_out;

  char* ws = (char*)d_ws;
  size_t off = 0;
  auto alloc = [&](size_t bytes) -> void* {
    void* p = ws + off;
    off += (bytes + 255) & ~(size_t)255;
    return p;
  };
  unsigned short* ctx_bf = (unsigned short*)alloc((size_t)B * H * CL * 2);    // 8.4 MB
  unsigned short* ctxwT  = (unsigned short*)alloc((size_t)B * CL * H * 2);    // 8.4 MB
  unsigned short* qry_bf = (unsigned short*)alloc((size_t)B * H * QL * 2);    // 1.05 MB
  unsigned short* qryT   = (unsigned short*)alloc((size_t)B * QL * H * 2);    // 1.05 MB
  unsigned short* eu     = (unsigned short*)alloc((size_t)B * QL * CL * 2);   // 16.8 MB
  unsigned short* tpart  = (unsigned short*)alloc((size_t)SPLITK5 * B * QL * H * 2); // 8.4 MB
  unsigned short* tT_bf  = (unsigned short*)alloc((size_t)B * H * QL * 2);    // 1.05 MB
  float* pct   = (float*)alloc((size_t)2 * B * CL * sizeof(float));
  float* pqt   = (float*)alloc((size_t)2 * B * QL * sizeof(float));
  float* rsum_ = (float*)alloc((size_t)B * CL * sizeof(float));
  float* Lpart = (float*)alloc((size_t)B * 64 * QL * sizeof(float));          // 1 MB

  ktrans_all<<<dim3(CL / 64 + QL / 64, H / 64, B), dim3(256), 0, stream>>>(
      context, question, w, ctx_bf, ctxwT, qry_bf, qryT, pct, pqt, out);

  k2_score5<<<dim3((CL / 32) * B), dim3(512), 0, stream>>>(
      ctxwT, qryT, pct, pqt, c_mask, q_mask, eu, rsum_, Lpart);

  k5_tpart<<<dim3((QL / 32) * SPLITK5 * B), dim3(256), 0, stream>>>(
      eu, ctx_bf, c_mask, tpart);

  k5b_treduce<<<dim3(QL / 64, H / 16, B), dim3(256), 0, stream>>>(
      tpart, Lpart, tT_bf);

  kb_out<<<dim3((CL / 64) * B), dim3(512), 0, stream>>>(
      eu, qry_bf, tT_bf, ctx_bf, rsum_, out);
}